// Round 1
// baseline (11857.989 us; speedup 1.0000x reference)
//
#include <hip/hip_runtime.h>

typedef _Float16 f16;
typedef _Float16 f16x8 __attribute__((ext_vector_type(8)));
typedef float f32x4 __attribute__((ext_vector_type(4)));

#define T_STEPS 256
#define I_DIM   512
#define H_DIM   512
#define TI      (T_STEPS * I_DIM)
#define ROWS    16
#define NPW     32
#define PADC    520
#define MATSZ   262144

// Pack w_hr|w_hz|w_hh into per-lane MFMA B-fragment order, fp16.
// Layout: wf[mat][nt(32)][kk(16)][lane(64)][j(8)]; element = W[k][n],
// k = kk*32 + (lane>>4)*8 + j, n = nt*16 + (lane&15).
__global__ __launch_bounds__(256) void prep_weights(
    const float* __restrict__ w_hr, const float* __restrict__ w_hz,
    const float* __restrict__ w_hh, f16* __restrict__ wf)
{
    int idx = blockIdx.x * 256 + threadIdx.x;
    int mat = idx >> 18;
    int r   = idx & (MATSZ - 1);
    int nt  = r >> 13;
    int r1  = r & 8191;
    int kk  = r1 >> 9;
    int r2  = r1 & 511;
    int l   = r2 >> 3;
    int j   = r2 & 7;
    int k = kk * 32 + ((l >> 4) << 3) + j;
    int n = (nt << 4) + (l & 15);
    const float* W = (mat == 0) ? w_hr : (mat == 1) ? w_hz : w_hh;
    wf[idx] = (f16)W[k * H_DIM + n];
}

// 32 blocks x 1024 threads (16 waves). Block b owns rows [16b,16b+16).
// Wave w owns output cols [32w, 32w+32). Zero inter-block sync; h state in
// registers (lane keeps the 8 positions matching its MFMA D-fragment).
__global__ __launch_bounds__(1024) void grud_main(
    const float* __restrict__ data, const float* __restrict__ state,
    const float* __restrict__ w_dg_x, const float* __restrict__ w_dg_h,
    const float* __restrict__ w_xr, const float* __restrict__ w_mr,
    const float* __restrict__ w_xz, const float* __restrict__ w_mz,
    const float* __restrict__ w_xh, const float* __restrict__ w_mh,
    const float* __restrict__ b_dg_x, const float* __restrict__ b_dg_h,
    const float* __restrict__ b_r, const float* __restrict__ b_z,
    const float* __restrict__ b_h,
    const f16* __restrict__ wf, float* __restrict__ out)
{
    __shared__ f16 hdec_l[ROWS][PADC];   // decayed h, fp16 A-operand
    __shared__ f16 rh_l[ROWS][PADC];     // r*h, fp16 A-operand

    const int tid = threadIdx.x;
    const int w   = tid >> 6;
    const int l   = tid & 63;
    const int lhi = l >> 4;       // 0..3
    const int llo = l & 15;       // 0..15
    const int n0  = w * NPW;
    const int rowbase = blockIdx.x * ROWS;

    const f16* wfr = wf + (size_t)(2 * w) * 8192;   // nt = 2w
    const f16* wfz = wfr + MATSZ;
    const f16* wfh = wfr + 2 * MATSZ;

    // lane-owned positions: rows lhi*4+reg (reg 0..3), cols n0+llo+16c (c 0..1)
    float h_reg[4][2];
    float hdec[4][2];
    float zreg[4][2];
    float ximp[4], mval[4];

#pragma unroll
    for (int reg = 0; reg < 4; ++reg) {
        int gi = rowbase + lhi * 4 + reg;
#pragma unroll
        for (int c = 0; c < 2; ++c)
            h_reg[reg][c] = state[(size_t)gi * H_DIM + n0 + llo + 16 * c];
    }

    for (int t = 0; t < T_STEPS; ++t) {
        // ---- S: per-row scalars + decay h, stage fp16 A tile ----
#pragma unroll
        for (int reg = 0; reg < 4; ++reg) {
            int i  = lhi * 4 + reg;
            int gi = rowbase + i;
            float d  = data[2 * TI + t * I_DIM + gi];
            float m  = data[1 * TI + t * I_DIM + gi];
            float x  = data[0 * TI + t * I_DIM + gi];
            float xp = data[3 * TI + t * I_DIM + gi];
            float gx = __expf(-fmaxf(w_dg_x[gi] * d + b_dg_x[gi], 0.0f));
            ximp[reg] = m * x + (1.0f - m) * (gx * xp);
            mval[reg] = m;
#pragma unroll
            for (int c = 0; c < 2; ++c) {
                int n = n0 + llo + 16 * c;
                float gh = __expf(-fmaxf(d * w_dg_h[n] + b_dg_h[(size_t)gi * H_DIM + n], 0.0f));
                float hd = gh * h_reg[reg][c];
                hdec[reg][c] = hd;
                hdec_l[i][n] = (f16)hd;
            }
        }
        __syncthreads();

        // ---- A: r,z GEMMs (K=512 in 16 chunks of 32) ----
        f32x4 acc_r0 = {0.f,0.f,0.f,0.f}, acc_r1 = {0.f,0.f,0.f,0.f};
        f32x4 acc_z0 = {0.f,0.f,0.f,0.f}, acc_z1 = {0.f,0.f,0.f,0.f};
#pragma unroll
        for (int kk = 0; kk < 16; ++kk) {
            f16x8 a = *(const f16x8*)&hdec_l[llo][kk * 32 + lhi * 8];
            const int fo = (kk * 64 + l) * 8;
            f16x8 br0 = *(const f16x8*)(wfr + fo);
            f16x8 br1 = *(const f16x8*)(wfr + 8192 + fo);
            f16x8 bz0 = *(const f16x8*)(wfz + fo);
            f16x8 bz1 = *(const f16x8*)(wfz + 8192 + fo);
            acc_r0 = __builtin_amdgcn_mfma_f32_16x16x32_f16(a, br0, acc_r0, 0, 0, 0);
            acc_r1 = __builtin_amdgcn_mfma_f32_16x16x32_f16(a, br1, acc_r1, 0, 0, 0);
            acc_z0 = __builtin_amdgcn_mfma_f32_16x16x32_f16(a, bz0, acc_z0, 0, 0, 0);
            acc_z1 = __builtin_amdgcn_mfma_f32_16x16x32_f16(a, bz1, acc_z1, 0, 0, 0);
        }
        // epilogue A: gates r,z; stage r*h fp16 tile
#pragma unroll
        for (int reg = 0; reg < 4; ++reg) {
            int i  = lhi * 4 + reg;
            int gi = rowbase + i;
#pragma unroll
            for (int c = 0; c < 2; ++c) {
                int n = n0 + llo + 16 * c;
                float sr = (c ? acc_r1[reg] : acc_r0[reg])
                         + ximp[reg] * w_xr[n] + mval[reg] * w_mr[n]
                         + b_r[(size_t)gi * H_DIM + n];
                float rr = 1.0f / (1.0f + __expf(-sr));
                float sz = (c ? acc_z1[reg] : acc_z0[reg])
                         + ximp[reg] * w_xz[n] + mval[reg] * w_mz[n]
                         + b_z[(size_t)gi * H_DIM + n];
                zreg[reg][c] = 1.0f / (1.0f + __expf(-sz));
                rh_l[i][n] = (f16)(rr * hdec[reg][c]);
            }
        }
        __syncthreads();

        // ---- B: h_tilde GEMM ----
        f32x4 acc_h0 = {0.f,0.f,0.f,0.f}, acc_h1 = {0.f,0.f,0.f,0.f};
#pragma unroll
        for (int kk = 0; kk < 16; ++kk) {
            f16x8 a = *(const f16x8*)&rh_l[llo][kk * 32 + lhi * 8];
            const int fo = (kk * 64 + l) * 8;
            f16x8 bh0 = *(const f16x8*)(wfh + fo);
            f16x8 bh1 = *(const f16x8*)(wfh + 8192 + fo);
            acc_h0 = __builtin_amdgcn_mfma_f32_16x16x32_f16(a, bh0, acc_h0, 0, 0, 0);
            acc_h1 = __builtin_amdgcn_mfma_f32_16x16x32_f16(a, bh1, acc_h1, 0, 0, 0);
        }
        // epilogue B: h_new, write output, update register state
#pragma unroll
        for (int reg = 0; reg < 4; ++reg) {
            int gi = rowbase + lhi * 4 + reg;
#pragma unroll
            for (int c = 0; c < 2; ++c) {
                int n = n0 + llo + 16 * c;
                float sh = (c ? acc_h1[reg] : acc_h0[reg])
                         + ximp[reg] * w_xh[n] + mval[reg] * w_mh[n]
                         + b_h[(size_t)gi * H_DIM + n];
                float e  = __expf(2.0f * sh);
                float th = 1.0f - 2.0f / (e + 1.0f);   // tanh(sh)
                float hn = (1.0f - zreg[reg][c]) * hdec[reg][c] + zreg[reg][c] * th;
                h_reg[reg][c] = hn;
                out[((size_t)t * I_DIM + gi) * H_DIM + n] = hn;
            }
        }
        // no barrier needed here: next S writes hdec_l, whose step-t readers
        // all passed bar2; rh_l is only rewritten after next bar1.
    }
}

extern "C" void kernel_launch(void* const* d_in, const int* in_sizes, int n_in,
                              void* d_out, int out_size, void* d_ws, size_t ws_size,
                              hipStream_t stream) {
    const float* data   = (const float*)d_in[0];
    const float* state  = (const float*)d_in[1];
    const float* w_dg_x = (const float*)d_in[2];
    const float* w_dg_h = (const float*)d_in[3];
    const float* w_xr   = (const float*)d_in[4];
    const float* w_hr   = (const float*)d_in[5];
    const float* w_mr   = (const float*)d_in[6];
    const float* w_xz   = (const float*)d_in[7];
    const float* w_hz   = (const float*)d_in[8];
    const float* w_mz   = (const float*)d_in[9];
    const float* w_xh   = (const float*)d_in[10];
    const float* w_hh   = (const float*)d_in[11];
    const float* w_mh   = (const float*)d_in[12];
    const float* b_dg_x = (const float*)d_in[13];
    const float* b_dg_h = (const float*)d_in[14];
    const float* b_r    = (const float*)d_in[15];
    const float* b_z    = (const float*)d_in[16];
    const float* b_h    = (const float*)d_in[17];
    f16* wf = (f16*)d_ws;          // 1.5 MB packed fp16 weights
    float* out = (float*)d_out;

    prep_weights<<<3072, 256, 0, stream>>>(w_hr, w_hz, w_hh, wf);
    grud_main<<<32, 1024, 0, stream>>>(data, state, w_dg_x, w_dg_h,
        w_xr, w_mr, w_xz, w_mz, w_xh, w_mh,
        b_dg_x, b_dg_h, b_r, b_z, b_h, wf, out);
}

// Round 2
// 10155.778 us; speedup vs baseline: 1.1676x; 1.1676x over previous
//
#include <hip/hip_runtime.h>

typedef _Float16 f16;
typedef _Float16 f16x8 __attribute__((ext_vector_type(8)));
typedef float f32x4 __attribute__((ext_vector_type(4)));

#define T_STEPS 256
#define I_DIM   512
#define H_DIM   512
#define TI      (T_STEPS * I_DIM)
#define ROWS    16
#define NPW     32
#define PADC    520
#define MATSZ   262144

// Pack w_hr|w_hz|w_hh into per-lane MFMA B-fragment order, fp16.
// Layout: wf[mat][nt(32)][kk(16)][lane(64)][j(8)]; element = W[k][n],
// k = kk*32 + (lane>>4)*8 + j, n = nt*16 + (lane&15).
__global__ __launch_bounds__(256) void prep_weights(
    const float* __restrict__ w_hr, const float* __restrict__ w_hz,
    const float* __restrict__ w_hh, f16* __restrict__ wf)
{
    int idx = blockIdx.x * 256 + threadIdx.x;
    int mat = idx >> 18;
    int r   = idx & (MATSZ - 1);
    int nt  = r >> 13;
    int r1  = r & 8191;
    int kk  = r1 >> 9;
    int r2  = r1 & 511;
    int l   = r2 >> 3;
    int j   = r2 & 7;
    int k = kk * 32 + ((l >> 4) << 3) + j;
    int n = (nt << 4) + (l & 15);
    const float* W = (mat == 0) ? w_hr : (mat == 1) ? w_hz : w_hh;
    wf[idx] = (f16)W[k * H_DIM + n];
}

// 32 blocks x 1024 threads (16 waves). Block b owns rows [16b,16b+16).
// Wave w owns output cols [32w, 32w+32). Zero inter-block sync; h state in
// registers. launch_bounds(1024,4): 16 waves/CU @ <=128 VGPR.
__global__ __launch_bounds__(1024, 4) void grud_main(
    const float* __restrict__ data, const float* __restrict__ state,
    const float* __restrict__ w_dg_x, const float* __restrict__ w_dg_h,
    const float* __restrict__ w_xr, const float* __restrict__ w_mr,
    const float* __restrict__ w_xz, const float* __restrict__ w_mz,
    const float* __restrict__ w_xh, const float* __restrict__ w_mh,
    const float* __restrict__ b_dg_x, const float* __restrict__ b_dg_h,
    const float* __restrict__ b_r, const float* __restrict__ b_z,
    const float* __restrict__ b_h,
    const f16* __restrict__ wf, float* __restrict__ out)
{
    __shared__ f16 hdec_l[ROWS][PADC];   // decayed h, fp16 A-operand
    __shared__ f16 rh_l[ROWS][PADC];     // r*h, fp16 A-operand
    __shared__ f16 bdg_l[ROWS][PADC];    // b_dg_h (t-invariant)
    __shared__ f16 br_l[ROWS][PADC];     // b_r
    __shared__ f16 bz_l[ROWS][PADC];     // b_z
    __shared__ f16 bh_l[ROWS][PADC];     // b_h
    __shared__ f16 wcol_l[7][H_DIM];     // w_dg_h,w_xr,w_mr,w_xz,w_mz,w_xh,w_mh
    __shared__ float wrow_l[2][ROWS];    // w_dg_x, b_dg_x (per-row)

    const int tid = threadIdx.x;
    const int w   = tid >> 6;
    const int l   = tid & 63;
    const int lhi = l >> 4;       // 0..3
    const int llo = l & 15;       // 0..15
    const int n0  = w * NPW;
    const int rowbase = blockIdx.x * ROWS;

    const f16* wfr = wf + (size_t)(2 * w) * 8192;   // nt = 2w
    const f16* wfz = wfr + MATSZ;
    const f16* wfh = wfr + 2 * MATSZ;

    // ---- stage t-invariant per-block data into LDS (once) ----
    for (int idx = tid; idx < ROWS * H_DIM; idx += 1024) {
        int i = idx >> 9, n = idx & 511;
        size_t g = (size_t)(rowbase + i) * H_DIM + n;
        bdg_l[i][n] = (f16)b_dg_h[g];
        br_l[i][n]  = (f16)b_r[g];
        bz_l[i][n]  = (f16)b_z[g];
        bh_l[i][n]  = (f16)b_h[g];
    }
    for (int n = tid; n < H_DIM; n += 1024) {
        wcol_l[0][n] = (f16)w_dg_h[n];
        wcol_l[1][n] = (f16)w_xr[n];
        wcol_l[2][n] = (f16)w_mr[n];
        wcol_l[3][n] = (f16)w_xz[n];
        wcol_l[4][n] = (f16)w_mz[n];
        wcol_l[5][n] = (f16)w_xh[n];
        wcol_l[6][n] = (f16)w_mh[n];
    }
    if (tid < ROWS) {
        wrow_l[0][tid] = w_dg_x[rowbase + tid];
        wrow_l[1][tid] = b_dg_x[rowbase + tid];
    }

    // lane-owned positions: rows lhi*4+reg (reg 0..3), cols n0+llo+16c (c 0..1)
    float h_reg[4][2];
    float hdec[4][2];
    float zreg[4][2];
    float ximp[4], mval[4];

#pragma unroll
    for (int reg = 0; reg < 4; ++reg) {
        int gi = rowbase + lhi * 4 + reg;
#pragma unroll
        for (int c = 0; c < 2; ++c)
            h_reg[reg][c] = state[(size_t)gi * H_DIM + n0 + llo + 16 * c];
    }
    __syncthreads();

    for (int t = 0; t < T_STEPS; ++t) {
        // ---- S: per-row scalars + decay h, stage fp16 A tile ----
#pragma unroll
        for (int reg = 0; reg < 4; ++reg) {
            int i  = lhi * 4 + reg;
            int gi = rowbase + i;
            float d  = data[2 * TI + t * I_DIM + gi];
            float m  = data[1 * TI + t * I_DIM + gi];
            float x  = data[0 * TI + t * I_DIM + gi];
            float xp = data[3 * TI + t * I_DIM + gi];
            float gx = __expf(-fmaxf(wrow_l[0][i] * d + wrow_l[1][i], 0.0f));
            ximp[reg] = m * x + (1.0f - m) * (gx * xp);
            mval[reg] = m;
#pragma unroll
            for (int c = 0; c < 2; ++c) {
                int n = n0 + llo + 16 * c;
                float gh = __expf(-fmaxf(d * (float)wcol_l[0][n] + (float)bdg_l[i][n], 0.0f));
                float hd = gh * h_reg[reg][c];
                hdec[reg][c] = hd;
                hdec_l[i][n] = (f16)hd;
            }
        }
        __syncthreads();

        // ---- A: r,z GEMMs, 2-deep ping-pong prefetch ----
        f32x4 acc_r0 = {0.f,0.f,0.f,0.f}, acc_r1 = {0.f,0.f,0.f,0.f};
        f32x4 acc_z0 = {0.f,0.f,0.f,0.f}, acc_z1 = {0.f,0.f,0.f,0.f};
        {
            f16x8 a_c, r0_c, r1_c, z0_c, z1_c;
            {
                const int fo = l * 8;
                a_c  = *(const f16x8*)&hdec_l[llo][lhi * 8];
                r0_c = *(const f16x8*)(wfr + fo);
                r1_c = *(const f16x8*)(wfr + 8192 + fo);
                z0_c = *(const f16x8*)(wfz + fo);
                z1_c = *(const f16x8*)(wfz + 8192 + fo);
            }
#pragma unroll
            for (int kk = 0; kk < 16; ++kk) {
                f16x8 a_n, r0_n, r1_n, z0_n, z1_n;
                if (kk < 15) {
                    const int fo = ((kk + 1) * 64 + l) * 8;
                    a_n  = *(const f16x8*)&hdec_l[llo][(kk + 1) * 32 + lhi * 8];
                    r0_n = *(const f16x8*)(wfr + fo);
                    r1_n = *(const f16x8*)(wfr + 8192 + fo);
                    z0_n = *(const f16x8*)(wfz + fo);
                    z1_n = *(const f16x8*)(wfz + 8192 + fo);
                }
                acc_r0 = __builtin_amdgcn_mfma_f32_16x16x32_f16(a_c, r0_c, acc_r0, 0, 0, 0);
                acc_r1 = __builtin_amdgcn_mfma_f32_16x16x32_f16(a_c, r1_c, acc_r1, 0, 0, 0);
                acc_z0 = __builtin_amdgcn_mfma_f32_16x16x32_f16(a_c, z0_c, acc_z0, 0, 0, 0);
                acc_z1 = __builtin_amdgcn_mfma_f32_16x16x32_f16(a_c, z1_c, acc_z1, 0, 0, 0);
                if (kk < 15) {
                    a_c = a_n; r0_c = r0_n; r1_c = r1_n; z0_c = z0_n; z1_c = z1_n;
                }
            }
        }
        // epilogue A: gates r,z; stage r*h fp16 tile (biases/weights from LDS)
#pragma unroll
        for (int reg = 0; reg < 4; ++reg) {
            int i  = lhi * 4 + reg;
#pragma unroll
            for (int c = 0; c < 2; ++c) {
                int n = n0 + llo + 16 * c;
                float sr = (c ? acc_r1[reg] : acc_r0[reg])
                         + ximp[reg] * (float)wcol_l[1][n] + mval[reg] * (float)wcol_l[2][n]
                         + (float)br_l[i][n];
                float rr = 1.0f / (1.0f + __expf(-sr));
                float sz = (c ? acc_z1[reg] : acc_z0[reg])
                         + ximp[reg] * (float)wcol_l[3][n] + mval[reg] * (float)wcol_l[4][n]
                         + (float)bz_l[i][n];
                zreg[reg][c] = 1.0f / (1.0f + __expf(-sz));
                rh_l[i][n] = (f16)(rr * hdec[reg][c]);
            }
        }
        __syncthreads();

        // ---- B: h_tilde GEMM, 2-deep ping-pong prefetch ----
        f32x4 acc_h0 = {0.f,0.f,0.f,0.f}, acc_h1 = {0.f,0.f,0.f,0.f};
        {
            f16x8 a_c, h0_c, h1_c;
            {
                const int fo = l * 8;
                a_c  = *(const f16x8*)&rh_l[llo][lhi * 8];
                h0_c = *(const f16x8*)(wfh + fo);
                h1_c = *(const f16x8*)(wfh + 8192 + fo);
            }
#pragma unroll
            for (int kk = 0; kk < 16; ++kk) {
                f16x8 a_n, h0_n, h1_n;
                if (kk < 15) {
                    const int fo = ((kk + 1) * 64 + l) * 8;
                    a_n  = *(const f16x8*)&rh_l[llo][(kk + 1) * 32 + lhi * 8];
                    h0_n = *(const f16x8*)(wfh + fo);
                    h1_n = *(const f16x8*)(wfh + 8192 + fo);
                }
                acc_h0 = __builtin_amdgcn_mfma_f32_16x16x32_f16(a_c, h0_c, acc_h0, 0, 0, 0);
                acc_h1 = __builtin_amdgcn_mfma_f32_16x16x32_f16(a_c, h1_c, acc_h1, 0, 0, 0);
                if (kk < 15) {
                    a_c = a_n; h0_c = h0_n; h1_c = h1_n;
                }
            }
        }
        // epilogue B: h_new, nontemporal write, update register state
#pragma unroll
        for (int reg = 0; reg < 4; ++reg) {
            int i  = lhi * 4 + reg;
            int gi = rowbase + i;
#pragma unroll
            for (int c = 0; c < 2; ++c) {
                int n = n0 + llo + 16 * c;
                float sh = (c ? acc_h1[reg] : acc_h0[reg])
                         + ximp[reg] * (float)wcol_l[5][n] + mval[reg] * (float)wcol_l[6][n]
                         + (float)bh_l[i][n];
                float e  = __expf(2.0f * sh);
                float th = 1.0f - 2.0f / (e + 1.0f);   // tanh(sh)
                float hn = (1.0f - zreg[reg][c]) * hdec[reg][c] + zreg[reg][c] * th;
                h_reg[reg][c] = hn;
                __builtin_nontemporal_store(hn, &out[((size_t)t * I_DIM + gi) * H_DIM + n]);
            }
        }
        // no barrier needed here: next S writes hdec_l, whose step-t readers
        // all passed bar2; rh_l is only rewritten after next bar1.
    }
}

extern "C" void kernel_launch(void* const* d_in, const int* in_sizes, int n_in,
                              void* d_out, int out_size, void* d_ws, size_t ws_size,
                              hipStream_t stream) {
    const float* data   = (const float*)d_in[0];
    const float* state  = (const float*)d_in[1];
    const float* w_dg_x = (const float*)d_in[2];
    const float* w_dg_h = (const float*)d_in[3];
    const float* w_xr   = (const float*)d_in[4];
    const float* w_hr   = (const float*)d_in[5];
    const float* w_mr   = (const float*)d_in[6];
    const float* w_xz   = (const float*)d_in[7];
    const float* w_hz   = (const float*)d_in[8];
    const float* w_mz   = (const float*)d_in[9];
    const float* w_xh   = (const float*)d_in[10];
    const float* w_hh   = (const float*)d_in[11];
    const float* w_mh   = (const float*)d_in[12];
    const float* b_dg_x = (const float*)d_in[13];
    const float* b_dg_h = (const float*)d_in[14];
    const float* b_r    = (const float*)d_in[15];
    const float* b_z    = (const float*)d_in[16];
    const float* b_h    = (const float*)d_in[17];
    f16* wf = (f16*)d_ws;          // 1.5 MB packed fp16 weights
    float* out = (float*)d_out;

    prep_weights<<<3072, 256, 0, stream>>>(w_hr, w_hz, w_hh, wf);
    grud_main<<<32, 1024, 0, stream>>>(data, state, w_dg_x, w_dg_h,
        w_xr, w_mr, w_xz, w_mz, w_xh, w_mh,
        b_dg_x, b_dg_h, b_r, b_z, b_h, wf, out);
}